// Round 1
// 615.117 us; speedup vs baseline: 2.2055x; 2.2055x over previous
//
#include <hip/hip_runtime.h>

#define Bn  32
#define IDF 1024
#define CDF 1024
#define Qn  2304
#define Sn  256

typedef _Float16 f16;
typedef _Float16 f16x2 __attribute__((ext_vector_type(2)));
typedef _Float16 f16x4 __attribute__((ext_vector_type(4)));
typedef _Float16 f16x8 __attribute__((ext_vector_type(8)));
typedef float    f32x4 __attribute__((ext_vector_type(4)));

// async global->LDS, 16B per lane; dest = wave-uniform base + lane*16
__device__ __forceinline__ void gll16(const void* g, void* l) {
    __builtin_amdgcn_global_load_lds((const __attribute__((address_space(1))) void*)g,
                                     (__attribute__((address_space(3))) void*)l, 16, 0, 0);
}

// split fp32 into fp16 hi + fp16 lo (x ~= hi + lo, error ~2^-23*|x|)
__device__ __forceinline__ void fsplit(float x, f16& hi, f16& lo) {
    hi = (f16)x;
    lo = (f16)(x - (float)hi);
}

// ---------------------------------------------------------------------------
// K1: srcT[b][i][s] = sum_c W[i][c] * ctx[b][c][s]   (fp32 VALU core, proven)
// Emits fp16 hi/lo in TWO layouts:
//   si_h/si_l: [b][s][IDF]  (k_attn B operand, k=i contiguous)
//   is_h/is_l: [b][i][Sn]   (k_wc  A operand, k=s contiguous)
// grid (Sn/64, IDF/64, Bn), block 256
// ---------------------------------------------------------------------------
__global__ __launch_bounds__(256) void k_srcT(const float* __restrict__ W,
                                              const float* __restrict__ ctx,
                                              f16* __restrict__ si_h, f16* __restrict__ si_l,
                                              f16* __restrict__ is_h, f16* __restrict__ is_l) {
    __shared__ float As[16][64];
    __shared__ float Bs[16][64];
    __shared__ alignas(16) float Sl[64][68];   // [s_local][i_local], 68 to keep float4 align + spread banks
    const int b  = blockIdx.z;
    const int i0 = blockIdx.y * 64;
    const int s0 = blockIdx.x * 64;
    const int tid = threadIdx.x;
    const int tx = tid & 15, ty = tid >> 4;
    const float* Cp = ctx + (size_t)b * CDF * Sn + s0;
    float acc[4][4] = {};
    for (int kk = 0; kk < CDF; kk += 16) {
        {
            const int i = tid >> 2, k4 = (tid & 3) * 4;
            const float4 a4 = *reinterpret_cast<const float4*>(&W[(size_t)(i0 + i) * CDF + kk + k4]);
            As[k4 + 0][i] = a4.x; As[k4 + 1][i] = a4.y;
            As[k4 + 2][i] = a4.z; As[k4 + 3][i] = a4.w;
        }
        #pragma unroll
        for (int it = 0; it < 4; ++it) {
            const int idx = it * 256 + tid;
            Bs[idx >> 6][idx & 63] = Cp[(size_t)(kk + (idx >> 6)) * Sn + (idx & 63)];
        }
        __syncthreads();
        #pragma unroll
        for (int k = 0; k < 16; ++k) {
            const float4 a4 = *reinterpret_cast<const float4*>(&As[k][ty * 4]);
            const float4 b4 = *reinterpret_cast<const float4*>(&Bs[k][tx * 4]);
            const float av[4] = {a4.x, a4.y, a4.z, a4.w};
            const float bv[4] = {b4.x, b4.y, b4.z, b4.w};
            #pragma unroll
            for (int r = 0; r < 4; ++r)
                #pragma unroll
                for (int c = 0; c < 4; ++c)
                    acc[r][c] = fmaf(av[r], bv[c], acc[r][c]);
        }
        __syncthreads();
    }
    // epilogue 1: i-major fp16 split, direct coalesced 8B stores
    #pragma unroll
    for (int r = 0; r < 4; ++r) {
        f16x4 h4, l4;
        #pragma unroll
        for (int c = 0; c < 4; ++c) { f16 h, l; fsplit(acc[r][c], h, l); h4[c] = h; l4[c] = l; }
        const size_t o = ((size_t)b * IDF + i0 + ty * 4 + r) * Sn + s0 + tx * 4;
        *reinterpret_cast<f16x4*>(&is_h[o]) = h4;
        *reinterpret_cast<f16x4*>(&is_l[o]) = l4;
    }
    // epilogue 2: s-major via LDS transpose
    #pragma unroll
    for (int c = 0; c < 4; ++c) {
        f32x4 v = {acc[0][c], acc[1][c], acc[2][c], acc[3][c]};
        *reinterpret_cast<f32x4*>(&Sl[tx * 4 + c][ty * 4]) = v;
    }
    __syncthreads();
    #pragma unroll
    for (int j = 0; j < 8; ++j) {
        const int colU = (tid & 15) + 16 * (j >> 2);   // i-pair column, 0..31
        const int s    = (tid >> 4) + 16 * (j & 3);    // 0..63
        const float p0 = Sl[s][2 * colU], p1 = Sl[s][2 * colU + 1];
        f16 h0, l0, h1, l1; fsplit(p0, h0, l0); fsplit(p1, h1, l1);
        const size_t o = ((size_t)b * Sn + s0 + s) * IDF + i0 + 2 * colU;
        f16x2 hh; hh[0] = h0; hh[1] = h1;
        f16x2 ll; ll[0] = l0; ll[1] = l1;
        *reinterpret_cast<f16x2*>(&si_h[o]) = hh;
        *reinterpret_cast<f16x2*>(&si_l[o]) = ll;
    }
}

// ---------------------------------------------------------------------------
// K2: logits via 3-term split-fp16 MFMA + fused masked softmax
//   C[q][s] = sum_i inp[b][i][q] * srcT[b][i][s]
// block = 256 thr (4 waves, 1x4 over s), tile 64q x 256s, K=IDF step 32
// wave w: q rows q0..q0+63 (mf*16 + g*4 + reg), s cols w*64 + nf*16 + l15
// A (inp, fp32 K-major) transposed+split in-kernel into LDS [q][32k] (80B rows)
// B (srcT fp16 hi/lo, [s][i]) staged linear via global_load_lds
// outputs: out1 = P^T fp32 [b][s][q]; Ph = P fp16 [b][q][s]
// ---------------------------------------------------------------------------
__global__ __launch_bounds__(256) void k_attn(const float* __restrict__ inp,
                                              const f16* __restrict__ si_h,
                                              const f16* __restrict__ si_l,
                                              const int* __restrict__ mask,
                                              float* __restrict__ out1,
                                              f16* __restrict__ Ph) {
    // LDS map (bytes):
    //   Ah [64][40 f16] @0      (5120)   Al @5120 (5120)
    //   Bh [256][32 f16] @10240 (16384)  Bl @26624 (16384)   total 43008
    //   union after K-loop: Pl f32 [128][68] @0 (34816), redm @34816, reds @35840
    __shared__ alignas(16) char smem[43008];
    const int tid = threadIdx.x;
    const int w = tid >> 6, lane = tid & 63, g = lane >> 4, l15 = lane & 15;

    // XCD-aware bijective swizzle (1152 = 8 * 144)
    const int lin = blockIdx.y * 36 + blockIdx.x;
    const int swz = (lin & 7) * 144 + (lin >> 3);
    const int b = swz / 36, qt = swz - b * 36;
    const int q0 = qt * 64;

    const float* Ap = inp + (size_t)b * IDF * Qn + q0;
    const f16* BhG = si_h + (size_t)b * Sn * IDF;
    const f16* BlG = si_l + (size_t)b * Sn * IDF;

    f32x4 acc[4][4];
    {
        f32x4 z = {0.f, 0.f, 0.f, 0.f};
        #pragma unroll
        for (int mf = 0; mf < 4; ++mf)
            #pragma unroll
            for (int nf = 0; nf < 4; ++nf)
                acc[mf][nf] = z;
    }

    for (int kk = 0; kk < IDF; kk += 32) {
        // ---- B staging: 2 x 16 KB via global_load_lds (linear dest) ----
        #pragma unroll
        for (int it = 0; it < 4; ++it) {
            const int byt = w * 4096 + it * 1024 + lane * 16;
            const int s = byt >> 6, ko = (byt & 63) >> 1;
            const size_t go = (size_t)s * IDF + kk + ko;
            gll16(BhG + go, smem + 10240 + w * 4096 + it * 1024);
            gll16(BlG + go, smem + 26624 + w * 4096 + it * 1024);
        }
        // ---- A staging: load fp32 coalesced, split, transpose-write ----
        float av[8];
        #pragma unroll
        for (int j = 0; j < 8; ++j)
            av[j] = Ap[(size_t)(kk + w * 8 + j) * Qn + lane];
        f16x8 ah, al;
        #pragma unroll
        for (int j = 0; j < 8; ++j) { f16 h, lo; fsplit(av[j], h, lo); ah[j] = h; al[j] = lo; }
        *reinterpret_cast<f16x8*>(smem + lane * 80 + w * 16) = ah;        // Ah[q=lane][k-chunk w*8]
        *reinterpret_cast<f16x8*>(smem + 5120 + lane * 80 + w * 16) = al;
        __syncthreads();

        // ---- fragments + MFMA ----
        f16x8 fah[4], fal[4];
        #pragma unroll
        for (int mf = 0; mf < 4; ++mf) {
            fah[mf] = *reinterpret_cast<const f16x8*>(smem + (mf * 16 + l15) * 80 + g * 16);
            fal[mf] = *reinterpret_cast<const f16x8*>(smem + 5120 + (mf * 16 + l15) * 80 + g * 16);
        }
        #pragma unroll
        for (int nf = 0; nf < 4; ++nf) {
            const int s = w * 64 + nf * 16 + l15;
            const f16x8 fbh = *reinterpret_cast<const f16x8*>(smem + 10240 + s * 64 + g * 16);
            const f16x8 fbl = *reinterpret_cast<const f16x8*>(smem + 26624 + s * 64 + g * 16);
            #pragma unroll
            for (int mf = 0; mf < 4; ++mf) {
                acc[mf][nf] = __builtin_amdgcn_mfma_f32_16x16x32_f16(fah[mf], fbh, acc[mf][nf], 0, 0, 0);
                acc[mf][nf] = __builtin_amdgcn_mfma_f32_16x16x32_f16(fah[mf], fbl, acc[mf][nf], 0, 0, 0);
                acc[mf][nf] = __builtin_amdgcn_mfma_f32_16x16x32_f16(fal[mf], fbh, acc[mf][nf], 0, 0, 0);
            }
        }
        __syncthreads();
    }

    // ---- masked softmax over s (rows q = mf*16+g*4+r; cols spread over waves) ----
    // mask row = (b*Qn + q) % Bn == q % 32 (Qn % 32 == 0, q0 % 32 == 0)
    int mv[2][4][4];
    #pragma unroll
    for (int h2 = 0; h2 < 2; ++h2)
        #pragma unroll
        for (int r = 0; r < 4; ++r)
            #pragma unroll
            for (int nf = 0; nf < 4; ++nf)
                mv[h2][r][nf] = mask[(h2 * 16 + g * 4 + r) * Sn + w * 64 + nf * 16 + l15];

    float* redm = reinterpret_cast<float*>(smem + 34816);  // [4 waves][64 q]
    float* reds = reinterpret_cast<float*>(smem + 35840);

    float mx[4][4], sm[4][4];
    #pragma unroll
    for (int mf = 0; mf < 4; ++mf)
        #pragma unroll
        for (int r = 0; r < 4; ++r) {
            float m = -3.0e38f;
            #pragma unroll
            for (int nf = 0; nf < 4; ++nf)
                if (!mv[mf & 1][r][nf]) m = fmaxf(m, acc[mf][nf][r]);
            m = fmaxf(m, __shfl_xor(m, 1, 64));
            m = fmaxf(m, __shfl_xor(m, 2, 64));
            m = fmaxf(m, __shfl_xor(m, 4, 64));
            m = fmaxf(m, __shfl_xor(m, 8, 64));
            mx[mf][r] = m;
        }
    if (l15 == 0) {
        #pragma unroll
        for (int mf = 0; mf < 4; ++mf)
            #pragma unroll
            for (int r = 0; r < 4; ++r)
                redm[w * 64 + mf * 16 + g * 4 + r] = mx[mf][r];
    }
    __syncthreads();
    #pragma unroll
    for (int mf = 0; mf < 4; ++mf)
        #pragma unroll
        for (int r = 0; r < 4; ++r) {
            const int q = mf * 16 + g * 4 + r;
            const float gm = fmaxf(fmaxf(redm[q], redm[64 + q]), fmaxf(redm[128 + q], redm[192 + q]));
            float ssum = 0.f;
            #pragma unroll
            for (int nf = 0; nf < 4; ++nf) {
                const float p = mv[mf & 1][r][nf] ? 0.f : __expf(acc[mf][nf][r] - gm);
                acc[mf][nf][r] = p;
                ssum += p;
            }
            ssum += __shfl_xor(ssum, 1, 64);
            ssum += __shfl_xor(ssum, 2, 64);
            ssum += __shfl_xor(ssum, 4, 64);
            ssum += __shfl_xor(ssum, 8, 64);
            sm[mf][r] = ssum;
        }
    if (l15 == 0) {
        #pragma unroll
        for (int mf = 0; mf < 4; ++mf)
            #pragma unroll
            for (int r = 0; r < 4; ++r)
                reds[w * 64 + mf * 16 + g * 4 + r] = sm[mf][r];
    }
    __syncthreads();
    #pragma unroll
    for (int mf = 0; mf < 4; ++mf)
        #pragma unroll
        for (int r = 0; r < 4; ++r) {
            const int q = mf * 16 + g * 4 + r;
            const float inv = 1.0f / (reds[q] + reds[64 + q] + reds[128 + q] + reds[192 + q]);
            #pragma unroll
            for (int nf = 0; nf < 4; ++nf)
                acc[mf][nf][r] *= inv;
        }

    // ---- outputs: out1 (P^T fp32) + Ph (P fp16, [q][s]) via LDS, 2 s-halves ----
    float* Pl = reinterpret_cast<float*>(smem);  // [128 s][68]
    float* O1 = out1 + (size_t)b * Sn * Qn + q0;
    f16* PhB = Ph + ((size_t)b * Qn + q0) * Sn;
    #pragma unroll
    for (int hf = 0; hf < 2; ++hf) {
        __syncthreads();
        if ((w >> 1) == hf) {   // waves {2hf, 2hf+1} own s = hf*128 .. +127
            #pragma unroll
            for (int mf = 0; mf < 4; ++mf)
                #pragma unroll
                for (int nf = 0; nf < 4; ++nf)
                    *reinterpret_cast<f32x4*>(
                        &Pl[((w & 1) * 64 + nf * 16 + l15) * 68 + mf * 16 + g * 4]) = acc[mf][nf];
        }
        __syncthreads();
        #pragma unroll
        for (int j = 0; j < 8; ++j) {
            const int sr = (tid >> 4) + j * 16;
            const int u  = (tid & 15) * 4;
            const f32x4 v = *reinterpret_cast<const f32x4*>(&Pl[sr * 68 + u]);
            *reinterpret_cast<f32x4*>(&O1[(size_t)(hf * 128 + sr) * Qn + u]) = v;
        }
        #pragma unroll
        for (int j = 0; j < 16; ++j) {
            const int colU = l15 + 16 * (j & 3);          // s-pair column 0..63
            const int q    = (w * 4 + g) + 16 * (j >> 2); // 0..63
            const float p0 = Pl[(2 * colU) * 68 + q];
            const float p1 = Pl[(2 * colU + 1) * 68 + q];
            f16x2 hh; hh[0] = (f16)p0; hh[1] = (f16)p1;
            *reinterpret_cast<f16x2*>(&PhB[(size_t)q * Sn + hf * 128 + 2 * colU]) = hh;
        }
    }
}

// ---------------------------------------------------------------------------
// K3: out0[b][i][q] = sum_s srcT[b][i][s] * P[b][q][s]   (2-term split MFMA)
// block 256 thr (4 waves 2x2), tile 128i x 128q, K=Sn step 32
// all operands fp16 linear -> pure global_load_lds staging (m97 structure)
// ---------------------------------------------------------------------------
__global__ __launch_bounds__(256) void k_wc(const f16* __restrict__ is_h,
                                            const f16* __restrict__ is_l,
                                            const f16* __restrict__ Ph,
                                            float* __restrict__ out0) {
    // Ah [128][32] @0 (8192), Al @8192, Bh [128][32] @16384
    __shared__ alignas(16) char smem[24576];
    const int tid = threadIdx.x;
    const int w = tid >> 6, lane = tid & 63, g = lane >> 4, l15 = lane & 15;
    const int wi = w >> 1, wq = w & 1;

    // bijective XCD swizzle (4608 = 8 * 576)
    const int lin = (blockIdx.z * 8 + blockIdx.y) * 18 + blockIdx.x;
    const int swz = (lin & 7) * 576 + (lin >> 3);
    const int b = swz / 144;
    const int rr = swz - b * 144;
    const int it = rr / 18, qt = rr - it * 18;
    const int i0 = it * 128, q0 = qt * 128;

    const f16* AhG = is_h + ((size_t)b * IDF + i0) * Sn;
    const f16* AlG = is_l + ((size_t)b * IDF + i0) * Sn;
    const f16* BG  = Ph  + ((size_t)b * Qn + q0) * Sn;

    f32x4 acc[4][4];
    {
        f32x4 z = {0.f, 0.f, 0.f, 0.f};
        #pragma unroll
        for (int mf = 0; mf < 4; ++mf)
            #pragma unroll
            for (int nf = 0; nf < 4; ++nf)
                acc[mf][nf] = z;
    }

    for (int kk = 0; kk < Sn; kk += 32) {
        #pragma unroll
        for (int t2 = 0; t2 < 2; ++t2) {
            const int byt = (w * 2 + t2) * 1024 + lane * 16;
            const int rw = byt >> 6, so = (byt & 63) >> 1;   // row (i or q), k-offset
            const size_t go = (size_t)rw * Sn + kk + so;
            gll16(AhG + go, smem + (w * 2 + t2) * 1024);
            gll16(AlG + go, smem + 8192 + (w * 2 + t2) * 1024);
            gll16(BG  + go, smem + 16384 + (w * 2 + t2) * 1024);
        }
        __syncthreads();
        f16x8 fah[4], fal[4];
        #pragma unroll
        for (int mf = 0; mf < 4; ++mf) {
            const int row = wi * 64 + mf * 16 + l15;
            fah[mf] = *reinterpret_cast<const f16x8*>(smem + row * 64 + g * 16);
            fal[mf] = *reinterpret_cast<const f16x8*>(smem + 8192 + row * 64 + g * 16);
        }
        #pragma unroll
        for (int nf = 0; nf < 4; ++nf) {
            const int row = wq * 64 + nf * 16 + l15;
            const f16x8 fbh = *reinterpret_cast<const f16x8*>(smem + 16384 + row * 64 + g * 16);
            #pragma unroll
            for (int mf = 0; mf < 4; ++mf) {
                acc[mf][nf] = __builtin_amdgcn_mfma_f32_16x16x32_f16(fah[mf], fbh, acc[mf][nf], 0, 0, 0);
                acc[mf][nf] = __builtin_amdgcn_mfma_f32_16x16x32_f16(fal[mf], fbh, acc[mf][nf], 0, 0, 0);
            }
        }
        __syncthreads();
    }
    float* O = out0 + ((size_t)b * IDF + i0 + wi * 64) * Qn + q0 + wq * 64;
    #pragma unroll
    for (int mf = 0; mf < 4; ++mf)
        #pragma unroll
        for (int nf = 0; nf < 4; ++nf)
            #pragma unroll
            for (int r = 0; r < 4; ++r)
                O[(size_t)(mf * 16 + g * 4 + r) * Qn + nf * 16 + l15] = acc[mf][nf][r];
}

extern "C" void kernel_launch(void* const* d_in, const int* in_sizes, int n_in,
                              void* d_out, int out_size, void* d_ws, size_t ws_size,
                              hipStream_t stream) {
    const float* inp  = (const float*)d_in[0];   // [B, IDF, 48, 48]
    const float* ctx  = (const float*)d_in[1];   // [B, CDF, S]
    const int*   mask = (const int*)  d_in[2];   // [B, S]
    const float* W    = (const float*)d_in[3];   // [IDF, CDF]
    float* out0 = (float*)d_out;                             // weightedContext
    float* out1 = out0 + (size_t)Bn * IDF * Qn;              // attn_out = P^T

    // workspace: 4 x 16 MiB srcT fp16 arrays + 36 MiB P fp16 = 100 MiB
    char* ws = (char*)d_ws;
    const size_t SZ = (size_t)Bn * Sn * IDF * sizeof(f16);   // 16 MiB
    f16* si_h = (f16*)(ws);
    f16* si_l = (f16*)(ws + SZ);
    f16* is_h = (f16*)(ws + 2 * SZ);
    f16* is_l = (f16*)(ws + 3 * SZ);
    f16* Ph   = (f16*)(ws + 4 * SZ);                         // [B][Q][S] fp16

    hipLaunchKernelGGL(k_srcT, dim3(Sn / 64, IDF / 64, Bn), dim3(256), 0, stream,
                       W, ctx, si_h, si_l, is_h, is_l);
    hipLaunchKernelGGL(k_attn, dim3(Qn / 64, Bn), dim3(256), 0, stream,
                       inp, si_h, si_l, mask, out1, Ph);
    hipLaunchKernelGGL(k_wc, dim3(Qn / 128, IDF / 128, Bn), dim3(256), 0, stream,
                       is_h, is_l, Ph, out0);
}

// Round 2
// 452.772 us; speedup vs baseline: 2.9964x; 1.3586x over previous
//
#include <hip/hip_runtime.h>

#define Bn  32
#define IDF 1024
#define CDF 1024
#define Qn  2304
#define Sn  256

typedef _Float16 f16;
typedef _Float16 f16x2 __attribute__((ext_vector_type(2)));
typedef _Float16 f16x4 __attribute__((ext_vector_type(4)));
typedef _Float16 f16x8 __attribute__((ext_vector_type(8)));
typedef float    f32x4 __attribute__((ext_vector_type(4)));

// async global->LDS, 16B per lane; dest = wave-uniform base + lane*16
__device__ __forceinline__ void gll16(const void* g, void* l) {
    __builtin_amdgcn_global_load_lds((const __attribute__((address_space(1))) void*)g,
                                     (__attribute__((address_space(3))) void*)l, 16, 0, 0);
}

// split fp32 into fp16 hi + fp16 lo (x ~= hi + lo, error ~2^-23*|x|)
__device__ __forceinline__ void fsplit(float x, f16& hi, f16& lo) {
    hi = (f16)x;
    lo = (f16)(x - (float)hi);
}

// ---------------------------------------------------------------------------
// K0: split W into fp16 hi/lo (runs once, ~4 MB traffic)
// ---------------------------------------------------------------------------
__global__ __launch_bounds__(256) void k_wsplit(const float* __restrict__ W,
                                                f16* __restrict__ Wh, f16* __restrict__ Wl) {
    const int idx = (blockIdx.x * 256 + threadIdx.x) * 4;
    const float4 v = *reinterpret_cast<const float4*>(&W[idx]);
    f16x4 h4, l4;
    f16 h, l;
    fsplit(v.x, h, l); h4[0] = h; l4[0] = l;
    fsplit(v.y, h, l); h4[1] = h; l4[1] = l;
    fsplit(v.z, h, l); h4[2] = h; l4[2] = l;
    fsplit(v.w, h, l); h4[3] = h; l4[3] = l;
    *reinterpret_cast<f16x4*>(&Wh[idx]) = h4;
    *reinterpret_cast<f16x4*>(&Wl[idx]) = l4;
}

// ---------------------------------------------------------------------------
// K1: srcT[b][i][s] = sum_c W[i][c] * ctx[b][c][s]  -- 3-term split-fp16 MFMA
// block 256 (4 waves 2x2), tile 128i x 128s, K=CDF step 32
// A (W hi/lo fp16, c-contig) staged linear via global_load_lds
// B (ctx fp32 [c][s]) loaded coalesced, split+transposed to LDS [s][c], 80B rows
// Emits fp16 hi/lo in TWO layouts:
//   si_h/si_l: [b][s][IDF]  (k_attn B operand)  -- direct f16x4 stores
//   is_h/is_l: [b][i][Sn]   (k_wc  A operand)  -- scalar f16 stores
// grid (Sn/128, IDF/128, Bn)
// ---------------------------------------------------------------------------
__global__ __launch_bounds__(256) void k_srcT(const f16* __restrict__ Wh,
                                              const f16* __restrict__ Wl,
                                              const float* __restrict__ ctx,
                                              f16* __restrict__ si_h, f16* __restrict__ si_l,
                                              f16* __restrict__ is_h, f16* __restrict__ is_l) {
    // LDS map: Ah [128][32 f16] @0 (8192), Al @8192 (8192)
    //          Ch [128 s][40 f16 = 80B] @16384 (10240), Cl @26624 (10240) = 36864 total
    __shared__ alignas(16) char smem[36864];
    const int tid = threadIdx.x;
    const int w = tid >> 6, lane = tid & 63, g = lane >> 4, l15 = lane & 15;
    const int wi = w >> 1, wq = w & 1;

    // bijective XCD swizzle over 512 blocks (512 % 8 == 0)
    const int lin = (blockIdx.z * 8 + blockIdx.y) * 2 + blockIdx.x;
    const int swz = (lin & 7) * 64 + (lin >> 3);
    const int b = swz >> 4, rr = swz & 15;
    const int i0 = (rr >> 1) * 128, s0 = (rr & 1) * 128;

    const float* Cp = ctx + (size_t)b * CDF * Sn + s0;
    const int sl = tid & 127, ch = tid >> 7;     // ctx staging: column s, c-chunk

    f32x4 acc[4][4];
    {
        f32x4 z = {0.f, 0.f, 0.f, 0.f};
        #pragma unroll
        for (int mf = 0; mf < 4; ++mf)
            #pragma unroll
            for (int nf = 0; nf < 4; ++nf)
                acc[mf][nf] = z;
    }

    for (int kk = 0; kk < CDF; kk += 32) {
        // ---- A staging: Wh/Wl [128 i][32 c], linear global_load_lds ----
        #pragma unroll
        for (int t2 = 0; t2 < 2; ++t2) {
            const int byt = (w * 2 + t2) * 1024 + lane * 16;
            const int rw = byt >> 6, co = (byt & 63) >> 1;
            const size_t go = (size_t)(i0 + rw) * CDF + kk + co;
            gll16(Wh + go, smem + (w * 2 + t2) * 1024);
            gll16(Wl + go, smem + 8192 + (w * 2 + t2) * 1024);
        }
        // ---- B staging: ctx [32 c][128 s] fp32 -> LDS [s][c] hi/lo ----
        float cv[16];
        #pragma unroll
        for (int j = 0; j < 16; ++j)
            cv[j] = Cp[(size_t)(kk + ch * 16 + j) * Sn + sl];
        f16x8 h0, h1, l0, l1;
        #pragma unroll
        for (int j = 0; j < 8; ++j) { f16 h, l; fsplit(cv[j], h, l); h0[j] = h; l0[j] = l; }
        #pragma unroll
        for (int j = 0; j < 8; ++j) { f16 h, l; fsplit(cv[8 + j], h, l); h1[j] = h; l1[j] = l; }
        char* cb = smem + 16384 + sl * 80 + ch * 32;
        *reinterpret_cast<f16x8*>(cb)              = h0;
        *reinterpret_cast<f16x8*>(cb + 16)         = h1;
        *reinterpret_cast<f16x8*>(cb + 10240)      = l0;
        *reinterpret_cast<f16x8*>(cb + 10240 + 16) = l1;
        __syncthreads();

        // ---- fragments + MFMA (3-term) ----
        f16x8 fah[4], fal[4];
        #pragma unroll
        for (int mf = 0; mf < 4; ++mf) {
            const int row = wi * 64 + mf * 16 + l15;
            fah[mf] = *reinterpret_cast<const f16x8*>(smem + row * 64 + g * 16);
            fal[mf] = *reinterpret_cast<const f16x8*>(smem + 8192 + row * 64 + g * 16);
        }
        #pragma unroll
        for (int nf = 0; nf < 4; ++nf) {
            const int srow = wq * 64 + nf * 16 + l15;
            const f16x8 fbh = *reinterpret_cast<const f16x8*>(smem + 16384 + srow * 80 + g * 16);
            const f16x8 fbl = *reinterpret_cast<const f16x8*>(smem + 26624 + srow * 80 + g * 16);
            #pragma unroll
            for (int mf = 0; mf < 4; ++mf) {
                acc[mf][nf] = __builtin_amdgcn_mfma_f32_16x16x32_f16(fah[mf], fbh, acc[mf][nf], 0, 0, 0);
                acc[mf][nf] = __builtin_amdgcn_mfma_f32_16x16x32_f16(fah[mf], fbl, acc[mf][nf], 0, 0, 0);
                acc[mf][nf] = __builtin_amdgcn_mfma_f32_16x16x32_f16(fal[mf], fbh, acc[mf][nf], 0, 0, 0);
            }
        }
        __syncthreads();
    }

    // ---- epilogue: split once, store both layouts ----
    #pragma unroll
    for (int mf = 0; mf < 4; ++mf)
        #pragma unroll
        for (int nf = 0; nf < 4; ++nf) {
            f16x4 h4, l4;
            #pragma unroll
            for (int r = 0; r < 4; ++r) { f16 h, l; fsplit(acc[mf][nf][r], h, l); h4[r] = h; l4[r] = l; }
            const int s  = s0 + wq * 64 + nf * 16 + l15;
            const int ib = i0 + wi * 64 + mf * 16 + g * 4;
            const size_t so = ((size_t)b * Sn + s) * IDF + ib;
            *reinterpret_cast<f16x4*>(&si_h[so]) = h4;
            *reinterpret_cast<f16x4*>(&si_l[so]) = l4;
            #pragma unroll
            for (int r = 0; r < 4; ++r) {
                const size_t io = ((size_t)b * IDF + ib + r) * Sn + s;
                is_h[io] = h4[r];
                is_l[io] = l4[r];
            }
        }
}

// ---------------------------------------------------------------------------
// K2: logits via 3-term split-fp16 MFMA + fused masked softmax (unchanged)
// ---------------------------------------------------------------------------
__global__ __launch_bounds__(256) void k_attn(const float* __restrict__ inp,
                                              const f16* __restrict__ si_h,
                                              const f16* __restrict__ si_l,
                                              const int* __restrict__ mask,
                                              float* __restrict__ out1,
                                              f16* __restrict__ Ph) {
    __shared__ alignas(16) char smem[43008];
    const int tid = threadIdx.x;
    const int w = tid >> 6, lane = tid & 63, g = lane >> 4, l15 = lane & 15;

    const int lin = blockIdx.y * 36 + blockIdx.x;
    const int swz = (lin & 7) * 144 + (lin >> 3);
    const int b = swz / 36, qt = swz - b * 36;
    const int q0 = qt * 64;

    const float* Ap = inp + (size_t)b * IDF * Qn + q0;
    const f16* BhG = si_h + (size_t)b * Sn * IDF;
    const f16* BlG = si_l + (size_t)b * Sn * IDF;

    f32x4 acc[4][4];
    {
        f32x4 z = {0.f, 0.f, 0.f, 0.f};
        #pragma unroll
        for (int mf = 0; mf < 4; ++mf)
            #pragma unroll
            for (int nf = 0; nf < 4; ++nf)
                acc[mf][nf] = z;
    }

    for (int kk = 0; kk < IDF; kk += 32) {
        #pragma unroll
        for (int it = 0; it < 4; ++it) {
            const int byt = w * 4096 + it * 1024 + lane * 16;
            const int s = byt >> 6, ko = (byt & 63) >> 1;
            const size_t go = (size_t)s * IDF + kk + ko;
            gll16(BhG + go, smem + 10240 + w * 4096 + it * 1024);
            gll16(BlG + go, smem + 26624 + w * 4096 + it * 1024);
        }
        float av[8];
        #pragma unroll
        for (int j = 0; j < 8; ++j)
            av[j] = Ap[(size_t)(kk + w * 8 + j) * Qn + lane];
        f16x8 ah, al;
        #pragma unroll
        for (int j = 0; j < 8; ++j) { f16 h, lo; fsplit(av[j], h, lo); ah[j] = h; al[j] = lo; }
        *reinterpret_cast<f16x8*>(smem + lane * 80 + w * 16) = ah;
        *reinterpret_cast<f16x8*>(smem + 5120 + lane * 80 + w * 16) = al;
        __syncthreads();

        f16x8 fah[4], fal[4];
        #pragma unroll
        for (int mf = 0; mf < 4; ++mf) {
            fah[mf] = *reinterpret_cast<const f16x8*>(smem + (mf * 16 + l15) * 80 + g * 16);
            fal[mf] = *reinterpret_cast<const f16x8*>(smem + 5120 + (mf * 16 + l15) * 80 + g * 16);
        }
        #pragma unroll
        for (int nf = 0; nf < 4; ++nf) {
            const int s = w * 64 + nf * 16 + l15;
            const f16x8 fbh = *reinterpret_cast<const f16x8*>(smem + 10240 + s * 64 + g * 16);
            const f16x8 fbl = *reinterpret_cast<const f16x8*>(smem + 26624 + s * 64 + g * 16);
            #pragma unroll
            for (int mf = 0; mf < 4; ++mf) {
                acc[mf][nf] = __builtin_amdgcn_mfma_f32_16x16x32_f16(fah[mf], fbh, acc[mf][nf], 0, 0, 0);
                acc[mf][nf] = __builtin_amdgcn_mfma_f32_16x16x32_f16(fah[mf], fbl, acc[mf][nf], 0, 0, 0);
                acc[mf][nf] = __builtin_amdgcn_mfma_f32_16x16x32_f16(fal[mf], fbh, acc[mf][nf], 0, 0, 0);
            }
        }
        __syncthreads();
    }

    int mv[2][4][4];
    #pragma unroll
    for (int h2 = 0; h2 < 2; ++h2)
        #pragma unroll
        for (int r = 0; r < 4; ++r)
            #pragma unroll
            for (int nf = 0; nf < 4; ++nf)
                mv[h2][r][nf] = mask[(h2 * 16 + g * 4 + r) * Sn + w * 64 + nf * 16 + l15];

    float* redm = reinterpret_cast<float*>(smem + 34816);
    float* reds = reinterpret_cast<float*>(smem + 35840);

    float mx[4][4], sm[4][4];
    #pragma unroll
    for (int mf = 0; mf < 4; ++mf)
        #pragma unroll
        for (int r = 0; r < 4; ++r) {
            float m = -3.0e38f;
            #pragma unroll
            for (int nf = 0; nf < 4; ++nf)
                if (!mv[mf & 1][r][nf]) m = fmaxf(m, acc[mf][nf][r]);
            m = fmaxf(m, __shfl_xor(m, 1, 64));
            m = fmaxf(m, __shfl_xor(m, 2, 64));
            m = fmaxf(m, __shfl_xor(m, 4, 64));
            m = fmaxf(m, __shfl_xor(m, 8, 64));
            mx[mf][r] = m;
        }
    if (l15 == 0) {
        #pragma unroll
        for (int mf = 0; mf < 4; ++mf)
            #pragma unroll
            for (int r = 0; r < 4; ++r)
                redm[w * 64 + mf * 16 + g * 4 + r] = mx[mf][r];
    }
    __syncthreads();
    #pragma unroll
    for (int mf = 0; mf < 4; ++mf)
        #pragma unroll
        for (int r = 0; r < 4; ++r) {
            const int q = mf * 16 + g * 4 + r;
            const float gm = fmaxf(fmaxf(redm[q], redm[64 + q]), fmaxf(redm[128 + q], redm[192 + q]));
            float ssum = 0.f;
            #pragma unroll
            for (int nf = 0; nf < 4; ++nf) {
                const float p = mv[mf & 1][r][nf] ? 0.f : __expf(acc[mf][nf][r] - gm);
                acc[mf][nf][r] = p;
                ssum += p;
            }
            ssum += __shfl_xor(ssum, 1, 64);
            ssum += __shfl_xor(ssum, 2, 64);
            ssum += __shfl_xor(ssum, 4, 64);
            ssum += __shfl_xor(ssum, 8, 64);
            sm[mf][r] = ssum;
        }
    if (l15 == 0) {
        #pragma unroll
        for (int mf = 0; mf < 4; ++mf)
            #pragma unroll
            for (int r = 0; r < 4; ++r)
                reds[w * 64 + mf * 16 + g * 4 + r] = sm[mf][r];
    }
    __syncthreads();
    #pragma unroll
    for (int mf = 0; mf < 4; ++mf)
        #pragma unroll
        for (int r = 0; r < 4; ++r) {
            const int q = mf * 16 + g * 4 + r;
            const float inv = 1.0f / (reds[q] + reds[64 + q] + reds[128 + q] + reds[192 + q]);
            #pragma unroll
            for (int nf = 0; nf < 4; ++nf)
                acc[mf][nf][r] *= inv;
        }

    float* Pl = reinterpret_cast<float*>(smem);
    float* O1 = out1 + (size_t)b * Sn * Qn + q0;
    f16* PhB = Ph + ((size_t)b * Qn + q0) * Sn;
    #pragma unroll
    for (int hf = 0; hf < 2; ++hf) {
        __syncthreads();
        if ((w >> 1) == hf) {
            #pragma unroll
            for (int mf = 0; mf < 4; ++mf)
                #pragma unroll
                for (int nf = 0; nf < 4; ++nf)
                    *reinterpret_cast<f32x4*>(
                        &Pl[((w & 1) * 64 + nf * 16 + l15) * 68 + mf * 16 + g * 4]) = acc[mf][nf];
        }
        __syncthreads();
        #pragma unroll
        for (int j = 0; j < 8; ++j) {
            const int sr = (tid >> 4) + j * 16;
            const int u  = (tid & 15) * 4;
            const f32x4 v = *reinterpret_cast<const f32x4*>(&Pl[sr * 68 + u]);
            *reinterpret_cast<f32x4*>(&O1[(size_t)(hf * 128 + sr) * Qn + u]) = v;
        }
        #pragma unroll
        for (int j = 0; j < 16; ++j) {
            const int colU = l15 + 16 * (j & 3);
            const int q    = (w * 4 + g) + 16 * (j >> 2);
            const float p0 = Pl[(2 * colU) * 68 + q];
            const float p1 = Pl[(2 * colU + 1) * 68 + q];
            f16x2 hh; hh[0] = (f16)p0; hh[1] = (f16)p1;
            *reinterpret_cast<f16x2*>(&PhB[(size_t)q * Sn + hf * 128 + 2 * colU]) = hh;
        }
    }
}

// ---------------------------------------------------------------------------
// K3: out0[b][i][q] = sum_s srcT[b][i][s] * P[b][q][s]   (unchanged)
// ---------------------------------------------------------------------------
__global__ __launch_bounds__(256) void k_wc(const f16* __restrict__ is_h,
                                            const f16* __restrict__ is_l,
                                            const f16* __restrict__ Ph,
                                            float* __restrict__ out0) {
    __shared__ alignas(16) char smem[24576];
    const int tid = threadIdx.x;
    const int w = tid >> 6, lane = tid & 63, g = lane >> 4, l15 = lane & 15;
    const int wi = w >> 1, wq = w & 1;

    const int lin = (blockIdx.z * 8 + blockIdx.y) * 18 + blockIdx.x;
    const int swz = (lin & 7) * 576 + (lin >> 3);
    const int b = swz / 144;
    const int rr = swz - b * 144;
    const int it = rr / 18, qt = rr - it * 18;
    const int i0 = it * 128, q0 = qt * 128;

    const f16* AhG = is_h + ((size_t)b * IDF + i0) * Sn;
    const f16* AlG = is_l + ((size_t)b * IDF + i0) * Sn;
    const f16* BG  = Ph  + ((size_t)b * Qn + q0) * Sn;

    f32x4 acc[4][4];
    {
        f32x4 z = {0.f, 0.f, 0.f, 0.f};
        #pragma unroll
        for (int mf = 0; mf < 4; ++mf)
            #pragma unroll
            for (int nf = 0; nf < 4; ++nf)
                acc[mf][nf] = z;
    }

    for (int kk = 0; kk < Sn; kk += 32) {
        #pragma unroll
        for (int t2 = 0; t2 < 2; ++t2) {
            const int byt = (w * 2 + t2) * 1024 + lane * 16;
            const int rw = byt >> 6, so = (byt & 63) >> 1;
            const size_t go = (size_t)rw * Sn + kk + so;
            gll16(AhG + go, smem + (w * 2 + t2) * 1024);
            gll16(AlG + go, smem + 8192 + (w * 2 + t2) * 1024);
            gll16(BG  + go, smem + 16384 + (w * 2 + t2) * 1024);
        }
        __syncthreads();
        f16x8 fah[4], fal[4];
        #pragma unroll
        for (int mf = 0; mf < 4; ++mf) {
            const int row = wi * 64 + mf * 16 + l15;
            fah[mf] = *reinterpret_cast<const f16x8*>(smem + row * 64 + g * 16);
            fal[mf] = *reinterpret_cast<const f16x8*>(smem + 8192 + row * 64 + g * 16);
        }
        #pragma unroll
        for (int nf = 0; nf < 4; ++nf) {
            const int row = wq * 64 + nf * 16 + l15;
            const f16x8 fbh = *reinterpret_cast<const f16x8*>(smem + 16384 + row * 64 + g * 16);
            #pragma unroll
            for (int mf = 0; mf < 4; ++mf) {
                acc[mf][nf] = __builtin_amdgcn_mfma_f32_16x16x32_f16(fah[mf], fbh, acc[mf][nf], 0, 0, 0);
                acc[mf][nf] = __builtin_amdgcn_mfma_f32_16x16x32_f16(fal[mf], fbh, acc[mf][nf], 0, 0, 0);
            }
        }
        __syncthreads();
    }
    float* O = out0 + ((size_t)b * IDF + i0 + wi * 64) * Qn + q0 + wq * 64;
    #pragma unroll
    for (int mf = 0; mf < 4; ++mf)
        #pragma unroll
        for (int nf = 0; nf < 4; ++nf)
            #pragma unroll
            for (int r = 0; r < 4; ++r)
                O[(size_t)(mf * 16 + g * 4 + r) * Qn + nf * 16 + l15] = acc[mf][nf][r];
}

extern "C" void kernel_launch(void* const* d_in, const int* in_sizes, int n_in,
                              void* d_out, int out_size, void* d_ws, size_t ws_size,
                              hipStream_t stream) {
    const float* inp  = (const float*)d_in[0];   // [B, IDF, 48, 48]
    const float* ctx  = (const float*)d_in[1];   // [B, CDF, S]
    const int*   mask = (const int*)  d_in[2];   // [B, S]
    const float* W    = (const float*)d_in[3];   // [IDF, CDF]
    float* out0 = (float*)d_out;                             // weightedContext
    float* out1 = out0 + (size_t)Bn * IDF * Qn;              // attn_out = P^T

    char* ws = (char*)d_ws;
    const size_t SZ = (size_t)Bn * Sn * IDF * sizeof(f16);   // 16 MiB
    f16* si_h = (f16*)(ws);
    f16* si_l = (f16*)(ws + SZ);
    f16* is_h = (f16*)(ws + 2 * SZ);
    f16* is_l = (f16*)(ws + 3 * SZ);
    f16* Ph   = (f16*)(ws + 4 * SZ);                         // [B][Q][S] fp16
    // W hi/lo alias the Ph region (dead until k_attn; k_srcT completes first)
    f16* Wh   = (f16*)(ws + 4 * SZ);
    f16* Wl   = Wh + (size_t)IDF * CDF;

    hipLaunchKernelGGL(k_wsplit, dim3(IDF * CDF / 1024), dim3(256), 0, stream, W, Wh, Wl);
    hipLaunchKernelGGL(k_srcT, dim3(Sn / 128, IDF / 128, Bn), dim3(256), 0, stream,
                       Wh, Wl, ctx, si_h, si_l, is_h, is_l);
    hipLaunchKernelGGL(k_attn, dim3(Qn / 64, Bn), dim3(256), 0, stream,
                       inp, si_h, si_l, mask, out1, Ph);
    hipLaunchKernelGGL(k_wc, dim3(Qn / 128, IDF / 128, Bn), dim3(256), 0, stream,
                       is_h, is_l, Ph, out0);
}